// Round 6
// baseline (1827.613 us; speedup 1.0000x reference)
//
#include <hip/hip_runtime.h>
#include <cmath>
#include <cstdint>

// HashPINN R5b:
//  - encode per-level serialized dispatches (R4 structure, featT as v2f).
//  - MLP on float2 ext-vectors -> v_pk_fma_f32 (packed fp32) if double-rate
//    on CDNA4; split into 8 dispatches so encode_levels shows up in the
//    profile top-5 (diagnostic for R6).
//  - nontemporal builtins require ext_vector_type, not HIP_vector_type.

#define HASH_SZ (1u << 19)
#define HMASK   (HASH_SZ - 1u)

typedef float v2f __attribute__((ext_vector_type(2)));

struct ResArr { int r[16]; };

__global__ __launch_bounds__(256, 8)
void encode_levels(const float* __restrict__ x,
                   const float* __restrict__ table,
                   v2f* __restrict__ featT,   // [16][n] float2
                   int n, int lb, int le, ResArr rv)
{
    const int nth = gridDim.x * 256;
    const int t0  = blockIdx.x * 256 + threadIdx.x;

    #pragma unroll 1
    for (int p = t0; p < n; p += nth) {
        const float px = __builtin_nontemporal_load(&x[3*p + 0]);
        const float py = __builtin_nontemporal_load(&x[3*p + 1]);
        const float pz = __builtin_nontemporal_load(&x[3*p + 2]);

        #pragma unroll 1
        for (int l = lb; l < le; ++l) {
            const int res = rv.r[l];
            const float rf = (float)(res - 1);
            const v2f* __restrict__ tbl = (const v2f*)table + (size_t)l * HASH_SZ;
            const bool dense = ((long long)res * res * res <= (long long)HASH_SZ);

            const float fx = px * rf, fy = py * rf, fz = pz * rf;
            int ix = (int)floorf(fx), iy = (int)floorf(fy), iz = (int)floorf(fz);
            ix = min(max(ix, 0), res - 2);
            iy = min(max(iy, 0), res - 2);
            iz = min(max(iz, 0), res - 2);
            const float tx = fx - (float)ix, ty = fy - (float)iy, tz = fz - (float)iz;
            const float sx = 1.f - tx, sy = 1.f - ty, sz = 1.f - tz;

            uint32_t idx[8];
            #pragma unroll
            for (int c = 0; c < 8; ++c) {
                const uint32_t cx = (uint32_t)(ix + ((c >> 2) & 1));
                const uint32_t cy = (uint32_t)(iy + ((c >> 1) & 1));
                const uint32_t cz = (uint32_t)(iz + (c & 1));
                if (dense) {  // wave-uniform (res uniform per level)
                    idx[c] = cx + (uint32_t)res * (cy + (uint32_t)res * cz);
                } else {
                    idx[c] = (cx * 1u ^ cy * 2654435761u ^ cz * 805459861u) & HMASK;
                }
            }
            v2f v[8];
            #pragma unroll
            for (int c = 0; c < 8; ++c) v[c] = tbl[idx[c]];

            float a0 = 0.f, a1 = 0.f;
            #pragma unroll
            for (int c = 0; c < 8; ++c) {
                const float wx = ((c >> 2) & 1) ? tx : sx;
                const float wy = ((c >> 1) & 1) ? ty : sy;
                const float wz = (c & 1) ? tz : sz;
                const float w = wx * wy * wz;
                a0 = fmaf(w, v[c].x, a0);
                a1 = fmaf(w, v[c].y, a1);
            }
            v2f st; st.x = a0; st.y = a1;
            __builtin_nontemporal_store(st, &featT[(size_t)l * n + p]);
        }
    }
}

__global__ __launch_bounds__(256, 3)
void mlp_forward(const v2f* __restrict__ featT,   // [16][n]
                 const float* __restrict__ W1, const float* __restrict__ b1,
                 const float* __restrict__ W2, const float* __restrict__ b2,
                 const float* __restrict__ W3, const float* __restrict__ b3,
                 const float* __restrict__ Wo, const float* __restrict__ bo,
                 float* __restrict__ out, int n, int p0, int cnt)
{
    const int i = blockIdx.x * 256 + threadIdx.x;
    if (i >= cnt) return;
    const int p = p0 + i;

    v2f A[32], B[32];

    // ---- layer 1: A = feat @ W1 + b1 (packed over output pairs) ----
    #pragma unroll
    for (int j = 0; j < 32; ++j) { v2f t = {b1[2*j], b1[2*j+1]}; A[j] = t; }
    #pragma unroll
    for (int l = 0; l < 16; ++l) {
        const v2f f = __builtin_nontemporal_load(&featT[(size_t)l * n + p]);
        const v2f h0 = {f.x, f.x};
        const v2f h1 = {f.y, f.y};
        const v2f* __restrict__ w0 = (const v2f*)(W1 + (size_t)(2*l)   * 64);
        const v2f* __restrict__ w1 = (const v2f*)(W1 + (size_t)(2*l+1) * 64);
        #pragma unroll
        for (int j = 0; j < 32; ++j) A[j] = __builtin_elementwise_fma(h0, w0[j], A[j]);
        #pragma unroll
        for (int j = 0; j < 32; ++j) A[j] = __builtin_elementwise_fma(h1, w1[j], A[j]);
    }

    // ---- layer 2: B = relu(A) @ W2 + b2 ----
    #pragma unroll
    for (int j = 0; j < 32; ++j) { v2f t = {b2[2*j], b2[2*j+1]}; B[j] = t; }
    #pragma unroll
    for (int k = 0; k < 64; ++k) {
        const float h = fmaxf(A[k >> 1][k & 1], 0.f);
        const v2f h2 = {h, h};
        const v2f* __restrict__ w = (const v2f*)(W2 + (size_t)k * 64);
        #pragma unroll
        for (int j = 0; j < 32; ++j) B[j] = __builtin_elementwise_fma(h2, w[j], B[j]);
    }

    // ---- layer 3 + output, fused in j-halves (keeps live regs bounded) ----
    float o = bo[0];
    #pragma unroll 1
    for (int hf = 0; hf < 2; ++hf) {
        const int j0 = hf * 32;   // output neurons [j0, j0+32)
        v2f C[16];
        #pragma unroll
        for (int j = 0; j < 16; ++j) { v2f t = {b3[j0 + 2*j], b3[j0 + 2*j + 1]}; C[j] = t; }
        #pragma unroll
        for (int k = 0; k < 64; ++k) {
            const float h = fmaxf(B[k >> 1][k & 1], 0.f);
            const v2f h2 = {h, h};
            const v2f* __restrict__ w = (const v2f*)(W3 + (size_t)k * 64 + j0);
            #pragma unroll
            for (int j = 0; j < 16; ++j) C[j] = __builtin_elementwise_fma(h2, w[j], C[j]);
        }
        const v2f* __restrict__ wo = (const v2f*)(Wo + j0);
        const v2f z2 = {0.f, 0.f};
        v2f o2 = z2;
        #pragma unroll
        for (int j = 0; j < 16; ++j) {
            const v2f r = __builtin_elementwise_max(C[j], z2);
            o2 = __builtin_elementwise_fma(r, wo[j], o2);
        }
        o += o2[0] + o2[1];
    }

    out[p] = o;
}

// Fallback (ws too small): R1-style fused kernel.
__global__ __launch_bounds__(256, 2)
void hashpinn_fused(const float* __restrict__ x,
                    const float* __restrict__ table,
                    const float* __restrict__ W1, const float* __restrict__ b1,
                    const float* __restrict__ W2, const float* __restrict__ b2,
                    const float* __restrict__ W3, const float* __restrict__ b3,
                    const float* __restrict__ Wo, const float* __restrict__ bo,
                    float* __restrict__ out, int n, ResArr rv)
{
    const int p = blockIdx.x * 256 + threadIdx.x;
    if (p >= n) return;
    const float px = x[3*p+0], py = x[3*p+1], pz = x[3*p+2];
    float feat[32];
    #pragma unroll
    for (int l = 0; l < 16; ++l) {
        const int res = rv.r[l];
        const float rf = (float)(res - 1);
        const float fx = px*rf, fy = py*rf, fz = pz*rf;
        int ix=(int)floorf(fx), iy=(int)floorf(fy), iz=(int)floorf(fz);
        ix=min(max(ix,0),res-2); iy=min(max(iy,0),res-2); iz=min(max(iz,0),res-2);
        const float tx=fx-(float)ix, ty=fy-(float)iy, tz=fz-(float)iz;
        const float sx=1.f-tx, sy=1.f-ty, sz=1.f-tz;
        const float2* tbl=(const float2*)table+(size_t)l*HASH_SZ;
        const bool dense=((long long)res*res*res<=(long long)HASH_SZ);
        float a0=0.f, a1=0.f;
        #pragma unroll
        for (int c=0;c<8;++c){
            const uint32_t cx=(uint32_t)(ix+((c>>2)&1));
            const uint32_t cy=(uint32_t)(iy+((c>>1)&1));
            const uint32_t cz=(uint32_t)(iz+(c&1));
            uint32_t idx = dense ? cx+(uint32_t)res*(cy+(uint32_t)res*cz)
                                 : ((cx*1u ^ cy*2654435761u ^ cz*805459861u)&HMASK);
            const float2 v=tbl[idx];
            const float w=(((c>>2)&1)?tx:sx)*(((c>>1)&1)?ty:sy)*((c&1)?tz:sz);
            a0=fmaf(w,v.x,a0); a1=fmaf(w,v.y,a1);
        }
        feat[2*l]=a0; feat[2*l+1]=a1;
    }
    float A[64], B[64];
    #pragma unroll
    for (int j=0;j<64;++j) A[j]=b1[j];
    #pragma unroll
    for (int k=0;k<32;++k){ const float h=feat[k];
        #pragma unroll
        for (int j=0;j<64;++j) A[j]=fmaf(h,W1[k*64+j],A[j]); }
    #pragma unroll 1
    for (int it=0;it<2;++it){
        const float* W = it?W3:W2; const float* bb = it?b3:b2;
        #pragma unroll
        for (int j=0;j<64;++j){ A[j]=fmaxf(A[j],0.f); B[j]=bb[j]; }
        #pragma unroll
        for (int k=0;k<64;++k){ const float h=A[k];
            #pragma unroll
            for (int j=0;j<64;++j) B[j]=fmaf(h,W[k*64+j],B[j]); }
        #pragma unroll
        for (int j=0;j<64;++j) A[j]=B[j];
    }
    float o=bo[0];
    #pragma unroll
    for (int j=0;j<64;++j) o=fmaf(fmaxf(A[j],0.f),Wo[j],o);
    out[p]=o;
}

extern "C" void kernel_launch(void* const* d_in, const int* in_sizes, int n_in,
                              void* d_out, int out_size, void* d_ws, size_t ws_size,
                              hipStream_t stream) {
    const float* x     = (const float*)d_in[0];
    const float* table = (const float*)d_in[1];
    const float* W1    = (const float*)d_in[2];
    const float* b1    = (const float*)d_in[3];
    const float* W2    = (const float*)d_in[4];
    const float* b2    = (const float*)d_in[5];
    const float* W3    = (const float*)d_in[6];
    const float* b3    = (const float*)d_in[7];
    const float* Wo    = (const float*)d_in[8];
    const float* bo    = (const float*)d_in[9];
    float* out = (float*)d_out;

    const int n = in_sizes[0] / 3;

    // numpy-matching resolutions via host libm
    ResArr rv;
    const double scale = std::exp2(std::log2(2048.0 / 16.0) / 15.0);
    for (int l = 0; l < 16; ++l)
        rv.r[l] = (int)std::ceil(16.0 * std::pow(scale, (double)l));

    // dense prefix: levels with res^3 <= HASH_SZ
    int dense_end = 0;
    while (dense_end < 16) {
        long long r = rv.r[dense_end];
        if (r * r * r <= (long long)HASH_SZ) ++dense_end; else break;
    }

    const size_t feat_bytes = (size_t)n * 16 * sizeof(v2f);

    if (ws_size >= feat_bytes) {
        v2f* featT = (v2f*)d_ws;
        const dim3 eg(4096), eb(256);
        if (dense_end > 0)
            hipLaunchKernelGGL(encode_levels, eg, eb, 0, stream,
                               x, table, featT, n, 0, dense_end, rv);
        for (int l = dense_end; l < 16; ++l)
            hipLaunchKernelGGL(encode_levels, eg, eb, 0, stream,
                               x, table, featT, n, l, l + 1, rv);

        // MLP in 8 sequential range-dispatches (graph replay makes the extra
        // launches ~free; lets encode_levels surface in the profile top-5).
        const int NSPLIT = 8;
        const int chunk = (n + NSPLIT - 1) / NSPLIT;
        for (int s = 0; s < NSPLIT; ++s) {
            const int p0 = s * chunk;
            const int cnt = (p0 + chunk <= n) ? chunk : (n - p0);
            if (cnt <= 0) break;
            hipLaunchKernelGGL(mlp_forward, dim3((cnt + 255) / 256), dim3(256), 0, stream,
                               featT, W1, b1, W2, b2, W3, b3, Wo, bo, out, n, p0, cnt);
        }
    } else {
        hipLaunchKernelGGL(hashpinn_fused, dim3((n + 255) / 256), dim3(256), 0, stream,
                           x, table, W1, b1, W2, b2, W3, b3, Wo, bo, out, n, rv);
    }
}

// Round 7
// 1348.991 us; speedup vs baseline: 1.3548x; 1.3548x over previous
//
#include <hip/hip_runtime.h>
#include <cmath>
#include <cstdint>

// HashPINN R7:
//  Encode is address-throughput bound (~2.2 cyc/lane-gather measured on the
//  all-cached dense phase). Cut gather count:
//   - corner pairs along x share one 16-B load: dense always (idx,idx+1);
//     hashed when ix even (hash uses prime 1 for x -> i1 = i0^1, same aligned
//     pair). Odd-ix lanes do a masked 8-B load for the second corner.
//   - 2 points/thread: vectorized x loads + featT stores, 2x gathers in
//     flight for L2-miss latency on fine levels.
//  MLP: float4 weight loads feeding 2x v_pk_fma_f32 each -> 2:1 VALU:VMEM
//  (was 1:1 -> VMEM-issue bound at ~500 us).

#define HASH_SZ (1u << 19)
#define HMASK   (HASH_SZ - 1u)
#define PR2 2654435761u
#define PR3 805459861u

typedef float v2f __attribute__((ext_vector_type(2)));
typedef float v4f __attribute__((ext_vector_type(4)));
typedef v4f v4fu __attribute__((aligned(8)));   // unaligned-16 (8-B) loads
typedef v2f v2fu __attribute__((aligned(8)));

struct ResArr { int r[16]; };

__device__ __forceinline__ void gather_one(
    const v2f* __restrict__ tbl, int res, bool dense,
    float px, float py, float pz, float& A0, float& A1)
{
    const float rf = (float)(res - 1);
    const float fx = px * rf, fy = py * rf, fz = pz * rf;
    int ix = (int)floorf(fx), iy = (int)floorf(fy), iz = (int)floorf(fz);
    ix = min(max(ix, 0), res - 2);
    iy = min(max(iy, 0), res - 2);
    iz = min(max(iz, 0), res - 2);
    const float tx = fx - (float)ix, ty = fy - (float)iy, tz = fz - (float)iz;
    const float sx = 1.f - tx, sy = 1.f - ty, sz = 1.f - tz;
    float a0 = 0.f, a1 = 0.f;

    if (dense) {
        // corners (ix,.) and (ix+1,.) are adjacent entries -> one 16-B load
        const int b0 = ix + res * (iy + res * iz);
        v4fu P[4];
        #pragma unroll
        for (int c = 0; c < 4; ++c) {
            const int dy = c >> 1, dz = c & 1;
            P[c] = *(const v4fu*)((const float*)tbl + 2 * (b0 + res * dy + res * res * dz));
        }
        #pragma unroll
        for (int c = 0; c < 4; ++c) {
            const int dy = c >> 1, dz = c & 1;
            const float wyz = (dy ? ty : sy) * (dz ? tz : sz);
            const float w0 = sx * wyz, w1 = tx * wyz;
            a0 = fmaf(w0, P[c].x, a0); a1 = fmaf(w0, P[c].y, a1);
            a0 = fmaf(w1, P[c].z, a0); a1 = fmaf(w1, P[c].w, a1);
        }
    } else {
        // hash: h = cx ^ cy*PR2 ^ cz*PR3 (prime for x is 1). For even ix:
        // i(ix+1) = i(ix)^1 -> both corners in one aligned 16-B pair.
        uint32_t i0[4], i1[4];
        v4f P[4];
        #pragma unroll
        for (int c = 0; c < 4; ++c) {
            const int dy = c >> 1, dz = c & 1;
            const uint32_t r = (uint32_t)(iy + dy) * PR2 ^ (uint32_t)(iz + dz) * PR3;
            i0[c] = ((uint32_t)ix ^ r) & HMASK;
            i1[c] = ((uint32_t)(ix + 1) ^ r) & HMASK;
            P[c] = *(const v4f*)((const float*)tbl + 2 * (i0[c] & ~1u));  // 16-B aligned
        }
        const bool odd = (ix & 1);
        v2f O[4];
        if (odd) {
            #pragma unroll
            for (int c = 0; c < 4; ++c) O[c] = tbl[i1[c]];
        } else {
            #pragma unroll
            for (int c = 0; c < 4; ++c) { v2f z = {0.f, 0.f}; O[c] = z; }
        }
        #pragma unroll
        for (int c = 0; c < 4; ++c) {
            const int dy = c >> 1, dz = c & 1;
            const bool hi = (i0[c] & 1);
            v2f c0, e;
            c0.x = hi ? P[c].z : P[c].x;  c0.y = hi ? P[c].w : P[c].y;
            e.x  = hi ? P[c].x : P[c].z;  e.y  = hi ? P[c].y : P[c].w;
            const v2f c1 = odd ? O[c] : e;
            const float wyz = (dy ? ty : sy) * (dz ? tz : sz);
            const float w0 = sx * wyz, w1 = tx * wyz;
            a0 = fmaf(w0, c0.x, a0); a1 = fmaf(w0, c0.y, a1);
            a0 = fmaf(w1, c1.x, a0); a1 = fmaf(w1, c1.y, a1);
        }
    }
    A0 = a0; A1 = a1;
}

template<int NLEV>
__global__ __launch_bounds__(256, 4)
void encode_k(const float* __restrict__ x, const float* __restrict__ table,
              v2f* __restrict__ featT, int n, int lb, ResArr rv)
{
    const int nth2 = gridDim.x * 512;
    for (int q = (blockIdx.x * 256 + threadIdx.x) * 2; q < n; q += nth2) {
        float p0x, p0y, p0z, p1x, p1y, p1z;
        const bool two = (q + 1 < n);
        if (two) {
            const v4fu a = __builtin_nontemporal_load((const v4fu*)(x + 3 * q));
            const v2f  b = __builtin_nontemporal_load((const v2fu*)(x + 3 * q + 4));
            p0x = a.x; p0y = a.y; p0z = a.z; p1x = a.w; p1y = b.x; p1z = b.y;
        } else {
            p0x = x[3 * q]; p0y = x[3 * q + 1]; p0z = x[3 * q + 2];
            p1x = p0x; p1y = p0y; p1z = p0z;
        }
        #pragma unroll
        for (int il = 0; il < NLEV; ++il) {
            const int l = lb + il;
            const int res = rv.r[l];
            const bool dense = ((long long)res * res * res <= (long long)HASH_SZ);
            const v2f* tbl = (const v2f*)table + (size_t)l * HASH_SZ;
            float a00, a01, a10, a11;
            gather_one(tbl, res, dense, p0x, p0y, p0z, a00, a01);
            gather_one(tbl, res, dense, p1x, p1y, p1z, a10, a11);
            if (two) {
                v4f st; st.x = a00; st.y = a01; st.z = a10; st.w = a11;
                __builtin_nontemporal_store(st, (v4f*)&featT[(size_t)l * n + q]);
            } else {
                v2f st; st.x = a00; st.y = a01;
                __builtin_nontemporal_store(st, &featT[(size_t)l * n + q]);
            }
        }
    }
}

__global__ __launch_bounds__(256, 3)
void mlp_forward(const v2f* __restrict__ featT,
                 const float* __restrict__ W1, const float* __restrict__ b1,
                 const float* __restrict__ W2, const float* __restrict__ b2,
                 const float* __restrict__ W3, const float* __restrict__ b3,
                 const float* __restrict__ Wo, const float* __restrict__ bo,
                 float* __restrict__ out, int n)
{
    const int p = blockIdx.x * 256 + threadIdx.x;
    if (p >= n) return;
    const v2f z2 = {0.f, 0.f};

    v2f A[32], B[32];

    // ---- layer 1 ----
    #pragma unroll
    for (int jq = 0; jq < 16; ++jq) {
        const v4f b = *(const v4f*)(b1 + 4 * jq);
        A[2 * jq] = b.xy; A[2 * jq + 1] = b.zw;
    }
    #pragma unroll
    for (int l = 0; l < 16; ++l) {
        const v2f f = __builtin_nontemporal_load(&featT[(size_t)l * n + p]);
        const v4f* w0 = (const v4f*)(W1 + (size_t)(2 * l) * 64);
        const v4f* w1 = (const v4f*)(W1 + (size_t)(2 * l + 1) * 64);
        const v2f h0 = {f.x, f.x}, h1 = {f.y, f.y};
        #pragma unroll
        for (int jq = 0; jq < 16; ++jq) {
            const v4f wa = w0[jq];
            A[2 * jq]     = __builtin_elementwise_fma(h0, wa.xy, A[2 * jq]);
            A[2 * jq + 1] = __builtin_elementwise_fma(h0, wa.zw, A[2 * jq + 1]);
        }
        #pragma unroll
        for (int jq = 0; jq < 16; ++jq) {
            const v4f wb = w1[jq];
            A[2 * jq]     = __builtin_elementwise_fma(h1, wb.xy, A[2 * jq]);
            A[2 * jq + 1] = __builtin_elementwise_fma(h1, wb.zw, A[2 * jq + 1]);
        }
    }
    #pragma unroll
    for (int j = 0; j < 32; ++j) A[j] = __builtin_elementwise_max(A[j], z2);

    // ---- layer 2 ----
    #pragma unroll
    for (int jq = 0; jq < 16; ++jq) {
        const v4f b = *(const v4f*)(b2 + 4 * jq);
        B[2 * jq] = b.xy; B[2 * jq + 1] = b.zw;
    }
    #pragma unroll
    for (int k = 0; k < 64; ++k) {
        const float hv = A[k >> 1][k & 1];
        const v2f h = {hv, hv};
        const v4f* w = (const v4f*)(W2 + (size_t)k * 64);
        #pragma unroll
        for (int jq = 0; jq < 16; ++jq) {
            const v4f wa = w[jq];
            B[2 * jq]     = __builtin_elementwise_fma(h, wa.xy, B[2 * jq]);
            B[2 * jq + 1] = __builtin_elementwise_fma(h, wa.zw, B[2 * jq + 1]);
        }
    }
    #pragma unroll
    for (int j = 0; j < 32; ++j) B[j] = __builtin_elementwise_max(B[j], z2);

    // ---- layer 3 ----
    #pragma unroll
    for (int jq = 0; jq < 16; ++jq) {
        const v4f b = *(const v4f*)(b3 + 4 * jq);
        A[2 * jq] = b.xy; A[2 * jq + 1] = b.zw;
    }
    #pragma unroll
    for (int k = 0; k < 64; ++k) {
        const float hv = B[k >> 1][k & 1];
        const v2f h = {hv, hv};
        const v4f* w = (const v4f*)(W3 + (size_t)k * 64);
        #pragma unroll
        for (int jq = 0; jq < 16; ++jq) {
            const v4f wa = w[jq];
            A[2 * jq]     = __builtin_elementwise_fma(h, wa.xy, A[2 * jq]);
            A[2 * jq + 1] = __builtin_elementwise_fma(h, wa.zw, A[2 * jq + 1]);
        }
    }

    // ---- output ----
    v2f o2 = z2;
    #pragma unroll
    for (int jq = 0; jq < 16; ++jq) {
        const v4f wa = *(const v4f*)(Wo + 4 * jq);
        o2 = __builtin_elementwise_fma(__builtin_elementwise_max(A[2 * jq], z2),     wa.xy, o2);
        o2 = __builtin_elementwise_fma(__builtin_elementwise_max(A[2 * jq + 1], z2), wa.zw, o2);
    }
    out[p] = o2.x + o2.y + bo[0];
}

// Fallback (ws too small): R1-style fused kernel.
__global__ __launch_bounds__(256, 2)
void hashpinn_fused(const float* __restrict__ x,
                    const float* __restrict__ table,
                    const float* __restrict__ W1, const float* __restrict__ b1,
                    const float* __restrict__ W2, const float* __restrict__ b2,
                    const float* __restrict__ W3, const float* __restrict__ b3,
                    const float* __restrict__ Wo, const float* __restrict__ bo,
                    float* __restrict__ out, int n, ResArr rv)
{
    const int p = blockIdx.x * 256 + threadIdx.x;
    if (p >= n) return;
    const float px = x[3*p+0], py = x[3*p+1], pz = x[3*p+2];
    float feat[32];
    #pragma unroll
    for (int l = 0; l < 16; ++l) {
        const int res = rv.r[l];
        const float rf = (float)(res - 1);
        const float fx = px*rf, fy = py*rf, fz = pz*rf;
        int ix=(int)floorf(fx), iy=(int)floorf(fy), iz=(int)floorf(fz);
        ix=min(max(ix,0),res-2); iy=min(max(iy,0),res-2); iz=min(max(iz,0),res-2);
        const float tx=fx-(float)ix, ty=fy-(float)iy, tz=fz-(float)iz;
        const float sx=1.f-tx, sy=1.f-ty, sz=1.f-tz;
        const float2* tbl=(const float2*)table+(size_t)l*HASH_SZ;
        const bool dense=((long long)res*res*res<=(long long)HASH_SZ);
        float a0=0.f, a1=0.f;
        #pragma unroll
        for (int c=0;c<8;++c){
            const uint32_t cx=(uint32_t)(ix+((c>>2)&1));
            const uint32_t cy=(uint32_t)(iy+((c>>1)&1));
            const uint32_t cz=(uint32_t)(iz+(c&1));
            uint32_t idx = dense ? cx+(uint32_t)res*(cy+(uint32_t)res*cz)
                                 : ((cx*1u ^ cy*PR2 ^ cz*PR3)&HMASK);
            const float2 v=tbl[idx];
            const float w=(((c>>2)&1)?tx:sx)*(((c>>1)&1)?ty:sy)*((c&1)?tz:sz);
            a0=fmaf(w,v.x,a0); a1=fmaf(w,v.y,a1);
        }
        feat[2*l]=a0; feat[2*l+1]=a1;
    }
    float A[64], B[64];
    #pragma unroll
    for (int j=0;j<64;++j) A[j]=b1[j];
    #pragma unroll
    for (int k=0;k<32;++k){ const float h=feat[k];
        #pragma unroll
        for (int j=0;j<64;++j) A[j]=fmaf(h,W1[k*64+j],A[j]); }
    #pragma unroll 1
    for (int it=0;it<2;++it){
        const float* W = it?W3:W2; const float* bb = it?b3:b2;
        #pragma unroll
        for (int j=0;j<64;++j){ A[j]=fmaxf(A[j],0.f); B[j]=bb[j]; }
        #pragma unroll
        for (int k=0;k<64;++k){ const float h=A[k];
            #pragma unroll
            for (int j=0;j<64;++j) B[j]=fmaf(h,W[k*64+j],B[j]); }
        #pragma unroll
        for (int j=0;j<64;++j) A[j]=B[j];
    }
    float o=bo[0];
    #pragma unroll
    for (int j=0;j<64;++j) o=fmaf(fmaxf(A[j],0.f),Wo[j],o);
    out[p]=o;
}

static inline void launch_encode(int nlev, const float* x, const float* table,
                                 v2f* featT, int n, int lb, const ResArr& rv,
                                 hipStream_t stream) {
    const dim3 g(2048), b(256);
    switch (nlev) {
        case 1: hipLaunchKernelGGL(encode_k<1>, g, b, 0, stream, x, table, featT, n, lb, rv); break;
        case 2: hipLaunchKernelGGL(encode_k<2>, g, b, 0, stream, x, table, featT, n, lb, rv); break;
        case 3: hipLaunchKernelGGL(encode_k<3>, g, b, 0, stream, x, table, featT, n, lb, rv); break;
        case 4: hipLaunchKernelGGL(encode_k<4>, g, b, 0, stream, x, table, featT, n, lb, rv); break;
        case 5: hipLaunchKernelGGL(encode_k<5>, g, b, 0, stream, x, table, featT, n, lb, rv); break;
        case 6: hipLaunchKernelGGL(encode_k<6>, g, b, 0, stream, x, table, featT, n, lb, rv); break;
        case 7: hipLaunchKernelGGL(encode_k<7>, g, b, 0, stream, x, table, featT, n, lb, rv); break;
        default: hipLaunchKernelGGL(encode_k<8>, g, b, 0, stream, x, table, featT, n, lb, rv); break;
    }
}

extern "C" void kernel_launch(void* const* d_in, const int* in_sizes, int n_in,
                              void* d_out, int out_size, void* d_ws, size_t ws_size,
                              hipStream_t stream) {
    const float* x     = (const float*)d_in[0];
    const float* table = (const float*)d_in[1];
    const float* W1    = (const float*)d_in[2];
    const float* b1    = (const float*)d_in[3];
    const float* W2    = (const float*)d_in[4];
    const float* b2    = (const float*)d_in[5];
    const float* W3    = (const float*)d_in[6];
    const float* b3    = (const float*)d_in[7];
    const float* Wo    = (const float*)d_in[8];
    const float* bo    = (const float*)d_in[9];
    float* out = (float*)d_out;

    const int n = in_sizes[0] / 3;

    // numpy-matching resolutions via host libm
    ResArr rv;
    const double scale = std::exp2(std::log2(2048.0 / 16.0) / 15.0);
    for (int l = 0; l < 16; ++l)
        rv.r[l] = (int)std::ceil(16.0 * std::pow(scale, (double)l));

    int dense_end = 0;
    while (dense_end < 16) {
        long long r = rv.r[dense_end];
        if (r * r * r <= (long long)HASH_SZ) ++dense_end; else break;
    }
    if (dense_end > 8) dense_end = 8;  // template bound (won't trigger: 5)

    const size_t feat_bytes = (size_t)n * 16 * sizeof(v2f);

    if (ws_size >= feat_bytes) {
        v2f* featT = (v2f*)d_ws;
        if (dense_end > 0)
            launch_encode(dense_end, x, table, featT, n, 0, rv, stream);
        for (int l = dense_end; l < 16; ++l)
            launch_encode(1, x, table, featT, n, l, rv, stream);

        hipLaunchKernelGGL(mlp_forward, dim3((n + 255) / 256), dim3(256), 0, stream,
                           featT, W1, b1, W2, b2, W3, b3, Wo, bo, out, n);
    } else {
        hipLaunchKernelGGL(hashpinn_fused, dim3((n + 255) / 256), dim3(256), 0, stream,
                           x, table, W1, b1, W2, b2, W3, b3, Wo, bo, out, n, rv);
    }
}

// Round 8
// 1124.103 us; speedup vs baseline: 1.6258x; 1.2001x over previous
//
#include <hip/hip_runtime.h>
#include <cmath>
#include <cstdint>

// HashPINN R8:
//  - Encode unchanged from R7 (corner pairing, 2 pts/thread, per-level phases).
//  - MLP rebuilt on bf16 MFMA with hi/lo split (xh*wh + xl*wh + xh*wl) for
//    fp32-grade accuracy at matrix-core rate. fp32 VALU floor was ~262 us
//    (v_pk_fma_f32 is NOT double rate on CDNA4 - R7 measured); MFMA path
//    needs ~60 us of matrix time.
//  - Weights pre-packed into B-fragment order (hi/lo) by prep_weights (40 KB
//    in d_ws after featT). Per-wave LDS transpose (stride 68) between layers.

#define HASH_SZ (1u << 19)
#define HMASK   (HASH_SZ - 1u)
#define PR2 2654435761u
#define PR3 805459861u

typedef float v2f __attribute__((ext_vector_type(2)));
typedef float v4f __attribute__((ext_vector_type(4)));
typedef v4f v4fu __attribute__((aligned(8)));
typedef v2f v2fu __attribute__((aligned(8)));
typedef short bf16x8 __attribute__((ext_vector_type(8)));
typedef float f32x4 __attribute__((ext_vector_type(4)));

struct ResArr { int r[16]; };

// ---------- bf16 helpers (RNE) ----------
__device__ __forceinline__ unsigned short bf16_rne(float f) {
    union { float f; unsigned u; } v; v.f = f;
    unsigned u = v.u;
    unsigned r = (u + 0x7fffu + ((u >> 16) & 1u)) >> 16;
    return (unsigned short)r;
}
__device__ __forceinline__ float bf16f(unsigned short h) {
    union { unsigned u; float f; } v; v.u = ((unsigned)h) << 16;
    return v.f;
}
__device__ __forceinline__ void split8(const float* x, bf16x8& hi, bf16x8& lo) {
    #pragma unroll
    for (int j = 0; j < 8; ++j) {
        unsigned short h = bf16_rne(x[j]);
        hi[j] = (short)h;
        lo[j] = (short)bf16_rne(x[j] - bf16f(h));
    }
}

// ---------------- encode (unchanged from R7) ----------------
__device__ __forceinline__ void gather_one(
    const v2f* __restrict__ tbl, int res, bool dense,
    float px, float py, float pz, float& A0, float& A1)
{
    const float rf = (float)(res - 1);
    const float fx = px * rf, fy = py * rf, fz = pz * rf;
    int ix = (int)floorf(fx), iy = (int)floorf(fy), iz = (int)floorf(fz);
    ix = min(max(ix, 0), res - 2);
    iy = min(max(iy, 0), res - 2);
    iz = min(max(iz, 0), res - 2);
    const float tx = fx - (float)ix, ty = fy - (float)iy, tz = fz - (float)iz;
    const float sx = 1.f - tx, sy = 1.f - ty, sz = 1.f - tz;
    float a0 = 0.f, a1 = 0.f;

    if (dense) {
        const int b0 = ix + res * (iy + res * iz);
        v4fu P[4];
        #pragma unroll
        for (int c = 0; c < 4; ++c) {
            const int dy = c >> 1, dz = c & 1;
            P[c] = *(const v4fu*)((const float*)tbl + 2 * (b0 + res * dy + res * res * dz));
        }
        #pragma unroll
        for (int c = 0; c < 4; ++c) {
            const int dy = c >> 1, dz = c & 1;
            const float wyz = (dy ? ty : sy) * (dz ? tz : sz);
            const float w0 = sx * wyz, w1 = tx * wyz;
            a0 = fmaf(w0, P[c].x, a0); a1 = fmaf(w0, P[c].y, a1);
            a0 = fmaf(w1, P[c].z, a0); a1 = fmaf(w1, P[c].w, a1);
        }
    } else {
        uint32_t i0[4], i1[4];
        v4f P[4];
        #pragma unroll
        for (int c = 0; c < 4; ++c) {
            const int dy = c >> 1, dz = c & 1;
            const uint32_t r = (uint32_t)(iy + dy) * PR2 ^ (uint32_t)(iz + dz) * PR3;
            i0[c] = ((uint32_t)ix ^ r) & HMASK;
            i1[c] = ((uint32_t)(ix + 1) ^ r) & HMASK;
            P[c] = *(const v4f*)((const float*)tbl + 2 * (i0[c] & ~1u));
        }
        const bool odd = (ix & 1);
        v2f O[4];
        if (odd) {
            #pragma unroll
            for (int c = 0; c < 4; ++c) O[c] = tbl[i1[c]];
        } else {
            #pragma unroll
            for (int c = 0; c < 4; ++c) { v2f z = {0.f, 0.f}; O[c] = z; }
        }
        #pragma unroll
        for (int c = 0; c < 4; ++c) {
            const int dy = c >> 1, dz = c & 1;
            const bool hi = (i0[c] & 1);
            v2f c0, e;
            c0.x = hi ? P[c].z : P[c].x;  c0.y = hi ? P[c].w : P[c].y;
            e.x  = hi ? P[c].x : P[c].z;  e.y  = hi ? P[c].y : P[c].w;
            const v2f c1 = odd ? O[c] : e;
            const float wyz = (dy ? ty : sy) * (dz ? tz : sz);
            const float w0 = sx * wyz, w1 = tx * wyz;
            a0 = fmaf(w0, c0.x, a0); a1 = fmaf(w0, c0.y, a1);
            a0 = fmaf(w1, c1.x, a0); a1 = fmaf(w1, c1.y, a1);
        }
    }
    A0 = a0; A1 = a1;
}

template<int NLEV>
__global__ __launch_bounds__(256, 4)
void encode_k(const float* __restrict__ x, const float* __restrict__ table,
              v2f* __restrict__ featT, int n, int lb, ResArr rv)
{
    const int nth2 = gridDim.x * 512;
    for (int q = (blockIdx.x * 256 + threadIdx.x) * 2; q < n; q += nth2) {
        float p0x, p0y, p0z, p1x, p1y, p1z;
        const bool two = (q + 1 < n);
        if (two) {
            const v4fu a = __builtin_nontemporal_load((const v4fu*)(x + 3 * q));
            const v2f  b = __builtin_nontemporal_load((const v2fu*)(x + 3 * q + 4));
            p0x = a.x; p0y = a.y; p0z = a.z; p1x = a.w; p1y = b.x; p1z = b.y;
        } else {
            p0x = x[3 * q]; p0y = x[3 * q + 1]; p0z = x[3 * q + 2];
            p1x = p0x; p1y = p0y; p1z = p0z;
        }
        #pragma unroll
        for (int il = 0; il < NLEV; ++il) {
            const int l = lb + il;
            const int res = rv.r[l];
            const bool dense = ((long long)res * res * res <= (long long)HASH_SZ);
            const v2f* tbl = (const v2f*)table + (size_t)l * HASH_SZ;
            float a00, a01, a10, a11;
            gather_one(tbl, res, dense, p0x, p0y, p0z, a00, a01);
            gather_one(tbl, res, dense, p1x, p1y, p1z, a10, a11);
            if (two) {
                v4f st; st.x = a00; st.y = a01; st.z = a10; st.w = a11;
                __builtin_nontemporal_store(st, (v4f*)&featT[(size_t)l * n + q]);
            } else {
                v2f st; st.x = a00; st.y = a01;
                __builtin_nontemporal_store(st, &featT[(size_t)l * n + q]);
            }
        }
    }
}

// ---------------- weight prep: pack B-fragments (hi/lo) ----------------
// Layout (ushort indices):
//  w1h: [nb][lane][j]        0 .. 2047     (nb<4, lane<64, j<8)
//  w1l:                       2048 .. 4095
//  w2h: [kb*4+nb][lane][j]   4096 .. 8191  (kb<2)
//  w2l:                       8192 .. 12287
//  w3h:                      12288 .. 16383
//  w3l:                      16384 .. 20479
__global__ void prep_weights(const float* __restrict__ W1,
                             const float* __restrict__ W2,
                             const float* __restrict__ W3,
                             unsigned short* __restrict__ wb)
{
    const int tid = threadIdx.x;          // 256 threads
    const int nb = tid >> 6, lane = tid & 63;
    const int l15 = lane & 15, q = lane >> 4;
    #pragma unroll
    for (int j = 0; j < 8; ++j) {
        const float v = W1[(q * 8 + j) * 64 + nb * 16 + l15];
        const unsigned short h = bf16_rne(v);
        wb[(nb * 64 + lane) * 8 + j] = h;
        wb[2048 + (nb * 64 + lane) * 8 + j] = bf16_rne(v - bf16f(h));
    }
    #pragma unroll
    for (int kb = 0; kb < 2; ++kb) {
        #pragma unroll
        for (int j = 0; j < 8; ++j) {
            const int row = kb * 32 + q * 8 + j;
            const int idx = ((kb * 4 + nb) * 64 + lane) * 8 + j;
            float v = W2[row * 64 + nb * 16 + l15];
            unsigned short h = bf16_rne(v);
            wb[4096 + idx] = h;
            wb[8192 + idx] = bf16_rne(v - bf16f(h));
            v = W3[row * 64 + nb * 16 + l15];
            h = bf16_rne(v);
            wb[12288 + idx] = h;
            wb[16384 + idx] = bf16_rne(v - bf16f(h));
        }
    }
}

// ---------------- MFMA MLP ----------------
__global__ __launch_bounds__(256, 4)
void mlp_mfma(const v2f* __restrict__ featT,
              const unsigned short* __restrict__ wb,
              const float* __restrict__ b1, const float* __restrict__ b2,
              const float* __restrict__ b3,
              const float* __restrict__ Wo, const float* __restrict__ bo,
              float* __restrict__ out, int n)
{
    __shared__ float sact[4][16 * 68];    // per-wave 16x64 transpose, stride 68
    const int wave = threadIdx.x >> 6;
    const int lane = threadIdx.x & 63;
    const int l15 = lane & 15, quad = lane >> 4;
    const int p0 = (blockIdx.x * 4 + wave) * 16;
    if (p0 >= n) return;
    const int p = p0 + l15;
    const int pl = (p < n) ? p : (n - 1);

    // ---- layer 1: A-frag straight from featT ----
    float xv[8];
    #pragma unroll
    for (int t = 0; t < 4; ++t) {
        const v2f f = featT[(size_t)(quad * 4 + t) * n + pl];
        xv[2 * t] = f.x; xv[2 * t + 1] = f.y;
    }
    bf16x8 ah, al;
    split8(xv, ah, al);

    f32x4 acc[4];
    #pragma unroll
    for (int nb = 0; nb < 4; ++nb) {
        const bf16x8 wh = *(const bf16x8*)(wb + (nb * 64 + lane) * 8);
        const bf16x8 wl = *(const bf16x8*)(wb + 2048 + (nb * 64 + lane) * 8);
        const float bv = b1[nb * 16 + l15];
        f32x4 c = {bv, bv, bv, bv};
        c = __builtin_amdgcn_mfma_f32_16x16x32_bf16(ah, wl, c, 0, 0, 0);
        c = __builtin_amdgcn_mfma_f32_16x16x32_bf16(al, wh, c, 0, 0, 0);
        c = __builtin_amdgcn_mfma_f32_16x16x32_bf16(ah, wh, c, 0, 0, 0);
        acc[nb] = c;
    }

    // hidden layers 2 and 3
    #pragma unroll
    for (int layer = 0; layer < 2; ++layer) {
        // relu -> LDS (D row = point = quad*4+r, col = neuron = nb*16+l15)
        #pragma unroll
        for (int nb = 0; nb < 4; ++nb)
            #pragma unroll
            for (int r = 0; r < 4; ++r)
                sact[wave][(quad * 4 + r) * 68 + nb * 16 + l15] = fmaxf(acc[nb][r], 0.f);

        // read back in A-frag order: A[m=l15][k=kb*32+quad*8+j]
        float x2[16];
        #pragma unroll
        for (int kb = 0; kb < 2; ++kb)
            #pragma unroll
            for (int j = 0; j < 8; ++j)
                x2[kb * 8 + j] = sact[wave][l15 * 68 + kb * 32 + quad * 8 + j];

        bf16x8 a2h[2], a2l[2];
        split8(x2, a2h[0], a2l[0]);
        split8(x2 + 8, a2h[1], a2l[1]);

        const int base_h = layer ? 12288 : 4096;
        const int base_l = layer ? 16384 : 8192;
        const float* __restrict__ bias = layer ? b3 : b2;
        #pragma unroll
        for (int nb = 0; nb < 4; ++nb) {
            const float bv = bias[nb * 16 + l15];
            f32x4 c = {bv, bv, bv, bv};
            #pragma unroll
            for (int kb = 0; kb < 2; ++kb) {
                const int idx = ((kb * 4 + nb) * 64 + lane) * 8;
                const bf16x8 wh = *(const bf16x8*)(wb + base_h + idx);
                const bf16x8 wl = *(const bf16x8*)(wb + base_l + idx);
                c = __builtin_amdgcn_mfma_f32_16x16x32_bf16(a2h[kb], wl, c, 0, 0, 0);
                c = __builtin_amdgcn_mfma_f32_16x16x32_bf16(a2l[kb], wh, c, 0, 0, 0);
                c = __builtin_amdgcn_mfma_f32_16x16x32_bf16(a2h[kb], wh, c, 0, 0, 0);
            }
            acc[nb] = c;
        }
    }

    // ---- output layer: VALU dot + 16-lane reduce ----
    float part[4];
    #pragma unroll
    for (int r = 0; r < 4; ++r) {
        float s = 0.f;
        #pragma unroll
        for (int nb = 0; nb < 4; ++nb)
            s = fmaf(fmaxf(acc[nb][r], 0.f), Wo[nb * 16 + l15], s);
        part[r] = s;
    }
    #pragma unroll
    for (int mask = 1; mask < 16; mask <<= 1)
        #pragma unroll
        for (int r = 0; r < 4; ++r)
            part[r] += __shfl_xor(part[r], mask, 64);

    if (l15 == 0) {
        const float b = bo[0];
        #pragma unroll
        for (int r = 0; r < 4; ++r) {
            const int po = p0 + quad * 4 + r;
            if (po < n) out[po] = part[r] + b;
        }
    }
}

// ---------------- fp32 MLP (ws-fallback path, from R7) ----------------
__global__ __launch_bounds__(256, 3)
void mlp_forward(const v2f* __restrict__ featT,
                 const float* __restrict__ W1, const float* __restrict__ b1,
                 const float* __restrict__ W2, const float* __restrict__ b2,
                 const float* __restrict__ W3, const float* __restrict__ b3,
                 const float* __restrict__ Wo, const float* __restrict__ bo,
                 float* __restrict__ out, int n)
{
    const int p = blockIdx.x * 256 + threadIdx.x;
    if (p >= n) return;
    const v2f z2 = {0.f, 0.f};
    v2f A[32], B[32];
    #pragma unroll
    for (int jq = 0; jq < 16; ++jq) {
        const v4f b = *(const v4f*)(b1 + 4 * jq);
        A[2 * jq] = b.xy; A[2 * jq + 1] = b.zw;
    }
    #pragma unroll
    for (int l = 0; l < 16; ++l) {
        const v2f f = __builtin_nontemporal_load(&featT[(size_t)l * n + p]);
        const v4f* w0 = (const v4f*)(W1 + (size_t)(2 * l) * 64);
        const v4f* w1 = (const v4f*)(W1 + (size_t)(2 * l + 1) * 64);
        const v2f h0 = {f.x, f.x}, h1 = {f.y, f.y};
        #pragma unroll
        for (int jq = 0; jq < 16; ++jq) {
            const v4f wa = w0[jq];
            A[2 * jq]     = __builtin_elementwise_fma(h0, wa.xy, A[2 * jq]);
            A[2 * jq + 1] = __builtin_elementwise_fma(h0, wa.zw, A[2 * jq + 1]);
        }
        #pragma unroll
        for (int jq = 0; jq < 16; ++jq) {
            const v4f wb2 = w1[jq];
            A[2 * jq]     = __builtin_elementwise_fma(h1, wb2.xy, A[2 * jq]);
            A[2 * jq + 1] = __builtin_elementwise_fma(h1, wb2.zw, A[2 * jq + 1]);
        }
    }
    #pragma unroll
    for (int j = 0; j < 32; ++j) A[j] = __builtin_elementwise_max(A[j], z2);
    #pragma unroll
    for (int jq = 0; jq < 16; ++jq) {
        const v4f b = *(const v4f*)(b2 + 4 * jq);
        B[2 * jq] = b.xy; B[2 * jq + 1] = b.zw;
    }
    #pragma unroll
    for (int k = 0; k < 64; ++k) {
        const float hv = A[k >> 1][k & 1];
        const v2f h = {hv, hv};
        const v4f* w = (const v4f*)(W2 + (size_t)k * 64);
        #pragma unroll
        for (int jq = 0; jq < 16; ++jq) {
            const v4f wa = w[jq];
            B[2 * jq]     = __builtin_elementwise_fma(h, wa.xy, B[2 * jq]);
            B[2 * jq + 1] = __builtin_elementwise_fma(h, wa.zw, B[2 * jq + 1]);
        }
    }
    #pragma unroll
    for (int j = 0; j < 32; ++j) B[j] = __builtin_elementwise_max(B[j], z2);
    #pragma unroll
    for (int jq = 0; jq < 16; ++jq) {
        const v4f b = *(const v4f*)(b3 + 4 * jq);
        A[2 * jq] = b.xy; A[2 * jq + 1] = b.zw;
    }
    #pragma unroll
    for (int k = 0; k < 64; ++k) {
        const float hv = B[k >> 1][k & 1];
        const v2f h = {hv, hv};
        const v4f* w = (const v4f*)(W3 + (size_t)k * 64);
        #pragma unroll
        for (int jq = 0; jq < 16; ++jq) {
            const v4f wa = w[jq];
            A[2 * jq]     = __builtin_elementwise_fma(h, wa.xy, A[2 * jq]);
            A[2 * jq + 1] = __builtin_elementwise_fma(h, wa.zw, A[2 * jq + 1]);
        }
    }
    v2f o2 = z2;
    #pragma unroll
    for (int jq = 0; jq < 16; ++jq) {
        const v4f wa = *(const v4f*)(Wo + 4 * jq);
        o2 = __builtin_elementwise_fma(__builtin_elementwise_max(A[2 * jq], z2),     wa.xy, o2);
        o2 = __builtin_elementwise_fma(__builtin_elementwise_max(A[2 * jq + 1], z2), wa.zw, o2);
    }
    out[p] = o2.x + o2.y + bo[0];
}

// ---------------- fallback (ws too small): R1-style fused ----------------
__global__ __launch_bounds__(256, 2)
void hashpinn_fused(const float* __restrict__ x,
                    const float* __restrict__ table,
                    const float* __restrict__ W1, const float* __restrict__ b1,
                    const float* __restrict__ W2, const float* __restrict__ b2,
                    const float* __restrict__ W3, const float* __restrict__ b3,
                    const float* __restrict__ Wo, const float* __restrict__ bo,
                    float* __restrict__ out, int n, ResArr rv)
{
    const int p = blockIdx.x * 256 + threadIdx.x;
    if (p >= n) return;
    const float px = x[3*p+0], py = x[3*p+1], pz = x[3*p+2];
    float feat[32];
    #pragma unroll
    for (int l = 0; l < 16; ++l) {
        const int res = rv.r[l];
        const float rf = (float)(res - 1);
        const float fx = px*rf, fy = py*rf, fz = pz*rf;
        int ix=(int)floorf(fx), iy=(int)floorf(fy), iz=(int)floorf(fz);
        ix=min(max(ix,0),res-2); iy=min(max(iy,0),res-2); iz=min(max(iz,0),res-2);
        const float tx=fx-(float)ix, ty=fy-(float)iy, tz=fz-(float)iz;
        const float sx=1.f-tx, sy=1.f-ty, sz=1.f-tz;
        const float2* tbl=(const float2*)table+(size_t)l*HASH_SZ;
        const bool dense=((long long)res*res*res<=(long long)HASH_SZ);
        float a0=0.f, a1=0.f;
        #pragma unroll
        for (int c=0;c<8;++c){
            const uint32_t cx=(uint32_t)(ix+((c>>2)&1));
            const uint32_t cy=(uint32_t)(iy+((c>>1)&1));
            const uint32_t cz=(uint32_t)(iz+(c&1));
            uint32_t idx = dense ? cx+(uint32_t)res*(cy+(uint32_t)res*cz)
                                 : ((cx*1u ^ cy*PR2 ^ cz*PR3)&HMASK);
            const float2 v=tbl[idx];
            const float w=(((c>>2)&1)?tx:sx)*(((c>>1)&1)?ty:sy)*((c&1)?tz:sz);
            a0=fmaf(w,v.x,a0); a1=fmaf(w,v.y,a1);
        }
        feat[2*l]=a0; feat[2*l+1]=a1;
    }
    float A[64], B[64];
    #pragma unroll
    for (int j=0;j<64;++j) A[j]=b1[j];
    #pragma unroll
    for (int k=0;k<32;++k){ const float h=feat[k];
        #pragma unroll
        for (int j=0;j<64;++j) A[j]=fmaf(h,W1[k*64+j],A[j]); }
    #pragma unroll 1
    for (int it=0;it<2;++it){
        const float* W = it?W3:W2; const float* bb = it?b3:b2;
        #pragma unroll
        for (int j=0;j<64;++j){ A[j]=fmaxf(A[j],0.f); B[j]=bb[j]; }
        #pragma unroll
        for (int k=0;k<64;++k){ const float h=A[k];
            #pragma unroll
            for (int j=0;j<64;++j) B[j]=fmaf(h,W[k*64+j],B[j]); }
        #pragma unroll
        for (int j=0;j<64;++j) A[j]=B[j];
    }
    float o=bo[0];
    #pragma unroll
    for (int j=0;j<64;++j) o=fmaf(fmaxf(A[j],0.f),Wo[j],o);
    out[p]=o;
}

static inline void launch_encode(int nlev, const float* x, const float* table,
                                 v2f* featT, int n, int lb, const ResArr& rv,
                                 hipStream_t stream) {
    const dim3 g(2048), b(256);
    switch (nlev) {
        case 1: hipLaunchKernelGGL(encode_k<1>, g, b, 0, stream, x, table, featT, n, lb, rv); break;
        case 2: hipLaunchKernelGGL(encode_k<2>, g, b, 0, stream, x, table, featT, n, lb, rv); break;
        case 3: hipLaunchKernelGGL(encode_k<3>, g, b, 0, stream, x, table, featT, n, lb, rv); break;
        case 4: hipLaunchKernelGGL(encode_k<4>, g, b, 0, stream, x, table, featT, n, lb, rv); break;
        case 5: hipLaunchKernelGGL(encode_k<5>, g, b, 0, stream, x, table, featT, n, lb, rv); break;
        case 6: hipLaunchKernelGGL(encode_k<6>, g, b, 0, stream, x, table, featT, n, lb, rv); break;
        case 7: hipLaunchKernelGGL(encode_k<7>, g, b, 0, stream, x, table, featT, n, lb, rv); break;
        default: hipLaunchKernelGGL(encode_k<8>, g, b, 0, stream, x, table, featT, n, lb, rv); break;
    }
}

extern "C" void kernel_launch(void* const* d_in, const int* in_sizes, int n_in,
                              void* d_out, int out_size, void* d_ws, size_t ws_size,
                              hipStream_t stream) {
    const float* x     = (const float*)d_in[0];
    const float* table = (const float*)d_in[1];
    const float* W1    = (const float*)d_in[2];
    const float* b1    = (const float*)d_in[3];
    const float* W2    = (const float*)d_in[4];
    const float* b2    = (const float*)d_in[5];
    const float* W3    = (const float*)d_in[6];
    const float* b3    = (const float*)d_in[7];
    const float* Wo    = (const float*)d_in[8];
    const float* bo    = (const float*)d_in[9];
    float* out = (float*)d_out;

    const int n = in_sizes[0] / 3;

    ResArr rv;
    const double scale = std::exp2(std::log2(2048.0 / 16.0) / 15.0);
    for (int l = 0; l < 16; ++l)
        rv.r[l] = (int)std::ceil(16.0 * std::pow(scale, (double)l));

    int dense_end = 0;
    while (dense_end < 16) {
        long long r = rv.r[dense_end];
        if (r * r * r <= (long long)HASH_SZ) ++dense_end; else break;
    }
    if (dense_end > 8) dense_end = 8;

    const size_t feat_bytes = (size_t)n * 16 * sizeof(v2f);
    const size_t wb_bytes = 20480 * sizeof(unsigned short);   // 40 KB packed weights

    if (ws_size >= feat_bytes + wb_bytes) {
        v2f* featT = (v2f*)d_ws;
        unsigned short* wb = (unsigned short*)((char*)d_ws + feat_bytes);

        hipLaunchKernelGGL(prep_weights, dim3(1), dim3(256), 0, stream, W1, W2, W3, wb);

        if (dense_end > 0)
            launch_encode(dense_end, x, table, featT, n, 0, rv, stream);
        for (int l = dense_end; l < 16; ++l)
            launch_encode(1, x, table, featT, n, l, rv, stream);

        const int nblocks = (n + 63) / 64;   // 64 points per block (4 waves x 16)
        hipLaunchKernelGGL(mlp_mfma, dim3(nblocks), dim3(256), 0, stream,
                           featT, wb, b1, b2, b3, Wo, bo, out, n);
    } else if (ws_size >= feat_bytes) {
        v2f* featT = (v2f*)d_ws;
        if (dense_end > 0)
            launch_encode(dense_end, x, table, featT, n, 0, rv, stream);
        for (int l = dense_end; l < 16; ++l)
            launch_encode(1, x, table, featT, n, l, rv, stream);
        hipLaunchKernelGGL(mlp_forward, dim3((n + 255) / 256), dim3(256), 0, stream,
                           featT, W1, b1, W2, b2, W3, b3, Wo, bo, out, n);
    } else {
        hipLaunchKernelGGL(hashpinn_fused, dim3((n + 255) / 256), dim3(256), 0, stream,
                           x, table, W1, b1, W2, b2, W3, b3, Wo, bo, out, n, rv);
    }
}

// Round 9
// 1084.936 us; speedup vs baseline: 1.6845x; 1.0361x over previous
//
#include <hip/hip_runtime.h>
#include <cmath>
#include <cstdint>

// HashPINN R9:
//  - Encode: R7 structure, launch_bounds back to (256,8) (hashed levels are
//    latency-exposed; want max waves), grid 4096 = single pass.
//  - MLP MFMA: 2 tiles (32 pts) per wave halves weight-load issue; split8 hi
//    via truncation (lo term captures the error exactly -> same 2^-17 bound,
//    ~35% fewer VALU ops); LDS transpose stride 68->65 (odd stride kills the
//    8-way bank conflict: 68 = 4 mod 32 made all addrs multiples of 4).

#define HASH_SZ (1u << 19)
#define HMASK   (HASH_SZ - 1u)
#define PR2 2654435761u
#define PR3 805459861u

typedef float v2f __attribute__((ext_vector_type(2)));
typedef float v4f __attribute__((ext_vector_type(4)));
typedef v4f v4fu __attribute__((aligned(8)));
typedef v2f v2fu __attribute__((aligned(8)));
typedef short bf16x8 __attribute__((ext_vector_type(8)));
typedef float f32x4 __attribute__((ext_vector_type(4)));

struct ResArr { int r[16]; };

// ---------- bf16 helpers ----------
__device__ __forceinline__ unsigned short bf16_rne(float f) {
    union { float f; unsigned u; } v; v.f = f;
    unsigned u = v.u;
    unsigned r = (u + 0x7fffu + ((u >> 16) & 1u)) >> 16;
    return (unsigned short)r;
}
__device__ __forceinline__ float bf16f(unsigned short h) {
    union { unsigned u; float f; } v; v.u = ((unsigned)h) << 16;
    return v.f;
}
// hi = TRUNCATED bf16 (cheap); lo = RNE bf16 of the exact remainder.
// x = hi + d exactly (d has the same exponent, low mantissa bits) ->
// |x - hi - lo| <= 2^-9 |d| <= 2^-17 |x|, same bound as RNE hi.
__device__ __forceinline__ void split8(const float* x, bf16x8& hi, bf16x8& lo) {
    #pragma unroll
    for (int j = 0; j < 8; ++j) {
        union { float f; unsigned u; } v; v.f = x[j];
        const unsigned hu = v.u & 0xffff0000u;
        hi[j] = (short)(hu >> 16);
        union { unsigned u; float f; } hf; hf.u = hu;
        const float d = x[j] - hf.f;
        union { float f; unsigned u; } dv; dv.f = d;
        lo[j] = (short)((dv.u + 0x7fffu + ((dv.u >> 16) & 1u)) >> 16);
    }
}

// ---------------- encode (R7 gather, (256,8)) ----------------
__device__ __forceinline__ void gather_one(
    const v2f* __restrict__ tbl, int res, bool dense,
    float px, float py, float pz, float& A0, float& A1)
{
    const float rf = (float)(res - 1);
    const float fx = px * rf, fy = py * rf, fz = pz * rf;
    int ix = (int)floorf(fx), iy = (int)floorf(fy), iz = (int)floorf(fz);
    ix = min(max(ix, 0), res - 2);
    iy = min(max(iy, 0), res - 2);
    iz = min(max(iz, 0), res - 2);
    const float tx = fx - (float)ix, ty = fy - (float)iy, tz = fz - (float)iz;
    const float sx = 1.f - tx, sy = 1.f - ty, sz = 1.f - tz;
    float a0 = 0.f, a1 = 0.f;

    if (dense) {
        const int b0 = ix + res * (iy + res * iz);
        v4fu P[4];
        #pragma unroll
        for (int c = 0; c < 4; ++c) {
            const int dy = c >> 1, dz = c & 1;
            P[c] = *(const v4fu*)((const float*)tbl + 2 * (b0 + res * dy + res * res * dz));
        }
        #pragma unroll
        for (int c = 0; c < 4; ++c) {
            const int dy = c >> 1, dz = c & 1;
            const float wyz = (dy ? ty : sy) * (dz ? tz : sz);
            const float w0 = sx * wyz, w1 = tx * wyz;
            a0 = fmaf(w0, P[c].x, a0); a1 = fmaf(w0, P[c].y, a1);
            a0 = fmaf(w1, P[c].z, a0); a1 = fmaf(w1, P[c].w, a1);
        }
    } else {
        uint32_t i0[4], i1[4];
        v4f P[4];
        #pragma unroll
        for (int c = 0; c < 4; ++c) {
            const int dy = c >> 1, dz = c & 1;
            const uint32_t r = (uint32_t)(iy + dy) * PR2 ^ (uint32_t)(iz + dz) * PR3;
            i0[c] = ((uint32_t)ix ^ r) & HMASK;
            i1[c] = ((uint32_t)(ix + 1) ^ r) & HMASK;
            P[c] = *(const v4f*)((const float*)tbl + 2 * (i0[c] & ~1u));
        }
        const bool odd = (ix & 1);
        v2f O[4];
        if (odd) {
            #pragma unroll
            for (int c = 0; c < 4; ++c) O[c] = tbl[i1[c]];
        } else {
            #pragma unroll
            for (int c = 0; c < 4; ++c) { v2f z = {0.f, 0.f}; O[c] = z; }
        }
        #pragma unroll
        for (int c = 0; c < 4; ++c) {
            const int dy = c >> 1, dz = c & 1;
            const bool hi = (i0[c] & 1);
            v2f c0, e;
            c0.x = hi ? P[c].z : P[c].x;  c0.y = hi ? P[c].w : P[c].y;
            e.x  = hi ? P[c].x : P[c].z;  e.y  = hi ? P[c].y : P[c].w;
            const v2f c1 = odd ? O[c] : e;
            const float wyz = (dy ? ty : sy) * (dz ? tz : sz);
            const float w0 = sx * wyz, w1 = tx * wyz;
            a0 = fmaf(w0, c0.x, a0); a1 = fmaf(w0, c0.y, a1);
            a0 = fmaf(w1, c1.x, a0); a1 = fmaf(w1, c1.y, a1);
        }
    }
    A0 = a0; A1 = a1;
}

template<int NLEV>
__global__ __launch_bounds__(256, 8)
void encode_k(const float* __restrict__ x, const float* __restrict__ table,
              v2f* __restrict__ featT, int n, int lb, ResArr rv)
{
    const int nth2 = gridDim.x * 512;
    for (int q = (blockIdx.x * 256 + threadIdx.x) * 2; q < n; q += nth2) {
        float p0x, p0y, p0z, p1x, p1y, p1z;
        const bool two = (q + 1 < n);
        if (two) {
            const v4fu a = __builtin_nontemporal_load((const v4fu*)(x + 3 * q));
            const v2f  b = __builtin_nontemporal_load((const v2fu*)(x + 3 * q + 4));
            p0x = a.x; p0y = a.y; p0z = a.z; p1x = a.w; p1y = b.x; p1z = b.y;
        } else {
            p0x = x[3 * q]; p0y = x[3 * q + 1]; p0z = x[3 * q + 2];
            p1x = p0x; p1y = p0y; p1z = p0z;
        }
        #pragma unroll
        for (int il = 0; il < NLEV; ++il) {
            const int l = lb + il;
            const int res = rv.r[l];
            const bool dense = ((long long)res * res * res <= (long long)HASH_SZ);
            const v2f* tbl = (const v2f*)table + (size_t)l * HASH_SZ;
            float a00, a01, a10, a11;
            gather_one(tbl, res, dense, p0x, p0y, p0z, a00, a01);
            gather_one(tbl, res, dense, p1x, p1y, p1z, a10, a11);
            if (two) {
                v4f st; st.x = a00; st.y = a01; st.z = a10; st.w = a11;
                __builtin_nontemporal_store(st, (v4f*)&featT[(size_t)l * n + q]);
            } else {
                v2f st; st.x = a00; st.y = a01;
                __builtin_nontemporal_store(st, &featT[(size_t)l * n + q]);
            }
        }
    }
}

// ---------------- weight prep (unchanged layout) ----------------
__global__ void prep_weights(const float* __restrict__ W1,
                             const float* __restrict__ W2,
                             const float* __restrict__ W3,
                             unsigned short* __restrict__ wb)
{
    const int tid = threadIdx.x;
    const int nb = tid >> 6, lane = tid & 63;
    const int l15 = lane & 15, q = lane >> 4;
    #pragma unroll
    for (int j = 0; j < 8; ++j) {
        const float v = W1[(q * 8 + j) * 64 + nb * 16 + l15];
        const unsigned short h = bf16_rne(v);
        wb[(nb * 64 + lane) * 8 + j] = h;
        wb[2048 + (nb * 64 + lane) * 8 + j] = bf16_rne(v - bf16f(h));
    }
    #pragma unroll
    for (int kb = 0; kb < 2; ++kb) {
        #pragma unroll
        for (int j = 0; j < 8; ++j) {
            const int row = kb * 32 + q * 8 + j;
            const int idx = ((kb * 4 + nb) * 64 + lane) * 8 + j;
            float v = W2[row * 64 + nb * 16 + l15];
            unsigned short h = bf16_rne(v);
            wb[4096 + idx] = h;
            wb[8192 + idx] = bf16_rne(v - bf16f(h));
            v = W3[row * 64 + nb * 16 + l15];
            h = bf16_rne(v);
            wb[12288 + idx] = h;
            wb[16384 + idx] = bf16_rne(v - bf16f(h));
        }
    }
}

// ---------------- MFMA MLP: 2 tiles (32 points) per wave ----------------
#define TSTR 65   // LDS row stride (odd -> banks spread, ~2-way max)

__global__ __launch_bounds__(256, 4)
void mlp_mfma(const v2f* __restrict__ featT,
              const unsigned short* __restrict__ wb,
              const float* __restrict__ b1, const float* __restrict__ b2,
              const float* __restrict__ b3,
              const float* __restrict__ Wo, const float* __restrict__ bo,
              float* __restrict__ out, int n)
{
    __shared__ float sact[4][32 * TSTR];
    const int wave = threadIdx.x >> 6;
    const int lane = threadIdx.x & 63;
    const int l15 = lane & 15, quad = lane >> 4;
    const int p0 = (blockIdx.x * 4 + wave) * 32;
    if (p0 >= n) return;

    // ---- layer 1: A-frags straight from featT ----
    bf16x8 ah[2], al[2];
    #pragma unroll
    for (int t = 0; t < 2; ++t) {
        const int p = p0 + t * 16 + l15;
        const int pl = (p < n) ? p : (n - 1);
        float xv[8];
        #pragma unroll
        for (int jj = 0; jj < 4; ++jj) {
            const v2f f = featT[(size_t)(quad * 4 + jj) * n + pl];
            xv[2 * jj] = f.x; xv[2 * jj + 1] = f.y;
        }
        split8(xv, ah[t], al[t]);
    }

    f32x4 acc[2][4];
    #pragma unroll
    for (int nb = 0; nb < 4; ++nb) {
        const bf16x8 wh = *(const bf16x8*)(wb + (nb * 64 + lane) * 8);
        const bf16x8 wl = *(const bf16x8*)(wb + 2048 + (nb * 64 + lane) * 8);
        const float bv = b1[nb * 16 + l15];
        #pragma unroll
        for (int t = 0; t < 2; ++t) {
            f32x4 c = {bv, bv, bv, bv};
            c = __builtin_amdgcn_mfma_f32_16x16x32_bf16(ah[t], wl, c, 0, 0, 0);
            c = __builtin_amdgcn_mfma_f32_16x16x32_bf16(al[t], wh, c, 0, 0, 0);
            c = __builtin_amdgcn_mfma_f32_16x16x32_bf16(ah[t], wh, c, 0, 0, 0);
            acc[t][nb] = c;
        }
    }

    // ---- hidden layers 2 & 3 ----
    #pragma unroll
    for (int layer = 0; layer < 2; ++layer) {
        // relu -> LDS transpose (per-wave private region, no barrier needed)
        #pragma unroll
        for (int t = 0; t < 2; ++t)
            #pragma unroll
            for (int nb = 0; nb < 4; ++nb)
                #pragma unroll
                for (int r = 0; r < 4; ++r)
                    sact[wave][(t * 16 + quad * 4 + r) * TSTR + nb * 16 + l15] =
                        fmaxf(acc[t][nb][r], 0.f);

        bf16x8 a2h[2][2], a2l[2][2];
        #pragma unroll
        for (int t = 0; t < 2; ++t) {
            float x2[16];
            #pragma unroll
            for (int kb = 0; kb < 2; ++kb)
                #pragma unroll
                for (int j = 0; j < 8; ++j)
                    x2[kb * 8 + j] =
                        sact[wave][(t * 16 + l15) * TSTR + kb * 32 + quad * 8 + j];
            split8(x2,     a2h[t][0], a2l[t][0]);
            split8(x2 + 8, a2h[t][1], a2l[t][1]);
        }

        const int base_h = layer ? 12288 : 4096;
        const int base_l = layer ? 16384 : 8192;
        const float* __restrict__ bias = layer ? b3 : b2;
        #pragma unroll
        for (int nb = 0; nb < 4; ++nb) {
            const float bv = bias[nb * 16 + l15];
            f32x4 c[2];
            #pragma unroll
            for (int t = 0; t < 2; ++t) { f32x4 z = {bv, bv, bv, bv}; c[t] = z; }
            #pragma unroll
            for (int kb = 0; kb < 2; ++kb) {
                const int idx = ((kb * 4 + nb) * 64 + lane) * 8;
                const bf16x8 wh = *(const bf16x8*)(wb + base_h + idx);
                const bf16x8 wl = *(const bf16x8*)(wb + base_l + idx);
                #pragma unroll
                for (int t = 0; t < 2; ++t) {
                    c[t] = __builtin_amdgcn_mfma_f32_16x16x32_bf16(a2h[t][kb], wl, c[t], 0, 0, 0);
                    c[t] = __builtin_amdgcn_mfma_f32_16x16x32_bf16(a2l[t][kb], wh, c[t], 0, 0, 0);
                    c[t] = __builtin_amdgcn_mfma_f32_16x16x32_bf16(a2h[t][kb], wh, c[t], 0, 0, 0);
                }
            }
            #pragma unroll
            for (int t = 0; t < 2; ++t) acc[t][nb] = c[t];
        }
    }

    // ---- output layer: VALU dot + 16-lane reduce ----
    const float wo = Wo[0 * 16 + l15];  // loaded per nb below
    (void)wo;
    float part[2][4];
    #pragma unroll
    for (int t = 0; t < 2; ++t)
        #pragma unroll
        for (int r = 0; r < 4; ++r) {
            float s = 0.f;
            #pragma unroll
            for (int nb = 0; nb < 4; ++nb)
                s = fmaf(fmaxf(acc[t][nb][r], 0.f), Wo[nb * 16 + l15], s);
            part[t][r] = s;
        }
    #pragma unroll
    for (int mask = 1; mask < 16; mask <<= 1)
        #pragma unroll
        for (int t = 0; t < 2; ++t)
            #pragma unroll
            for (int r = 0; r < 4; ++r)
                part[t][r] += __shfl_xor(part[t][r], mask, 64);

    if (l15 == 0) {
        const float b = bo[0];
        #pragma unroll
        for (int t = 0; t < 2; ++t)
            #pragma unroll
            for (int r = 0; r < 4; ++r) {
                const int po = p0 + t * 16 + quad * 4 + r;
                if (po < n) out[po] = part[t][r] + b;
            }
    }
}

// ---------------- fp32 MLP (ws-fallback path) ----------------
__global__ __launch_bounds__(256, 3)
void mlp_forward(const v2f* __restrict__ featT,
                 const float* __restrict__ W1, const float* __restrict__ b1,
                 const float* __restrict__ W2, const float* __restrict__ b2,
                 const float* __restrict__ W3, const float* __restrict__ b3,
                 const float* __restrict__ Wo, const float* __restrict__ bo,
                 float* __restrict__ out, int n)
{
    const int p = blockIdx.x * 256 + threadIdx.x;
    if (p >= n) return;
    const v2f z2 = {0.f, 0.f};
    v2f A[32], B[32];
    #pragma unroll
    for (int jq = 0; jq < 16; ++jq) {
        const v4f b = *(const v4f*)(b1 + 4 * jq);
        A[2 * jq] = b.xy; A[2 * jq + 1] = b.zw;
    }
    #pragma unroll
    for (int l = 0; l < 16; ++l) {
        const v2f f = __builtin_nontemporal_load(&featT[(size_t)l * n + p]);
        const v4f* w0 = (const v4f*)(W1 + (size_t)(2 * l) * 64);
        const v4f* w1 = (const v4f*)(W1 + (size_t)(2 * l + 1) * 64);
        const v2f h0 = {f.x, f.x}, h1 = {f.y, f.y};
        #pragma unroll
        for (int jq = 0; jq < 16; ++jq) {
            const v4f wa = w0[jq];
            A[2 * jq]     = __builtin_elementwise_fma(h0, wa.xy, A[2 * jq]);
            A[2 * jq + 1] = __builtin_elementwise_fma(h0, wa.zw, A[2 * jq + 1]);
        }
        #pragma unroll
        for (int jq = 0; jq < 16; ++jq) {
            const v4f wb2 = w1[jq];
            A[2 * jq]     = __builtin_elementwise_fma(h1, wb2.xy, A[2 * jq]);
            A[2 * jq + 1] = __builtin_elementwise_fma(h1, wb2.zw, A[2 * jq + 1]);
        }
    }
    #pragma unroll
    for (int j = 0; j < 32; ++j) A[j] = __builtin_elementwise_max(A[j], z2);
    #pragma unroll
    for (int jq = 0; jq < 16; ++jq) {
        const v4f b = *(const v4f*)(b2 + 4 * jq);
        B[2 * jq] = b.xy; B[2 * jq + 1] = b.zw;
    }
    #pragma unroll
    for (int k = 0; k < 64; ++k) {
        const float hv = A[k >> 1][k & 1];
        const v2f h = {hv, hv};
        const v4f* w = (const v4f*)(W2 + (size_t)k * 64);
        #pragma unroll
        for (int jq = 0; jq < 16; ++jq) {
            const v4f wa = w[jq];
            B[2 * jq]     = __builtin_elementwise_fma(h, wa.xy, B[2 * jq]);
            B[2 * jq + 1] = __builtin_elementwise_fma(h, wa.zw, B[2 * jq + 1]);
        }
    }
    #pragma unroll
    for (int j = 0; j < 32; ++j) B[j] = __builtin_elementwise_max(B[j], z2);
    #pragma unroll
    for (int jq = 0; jq < 16; ++jq) {
        const v4f b = *(const v4f*)(b3 + 4 * jq);
        A[2 * jq] = b.xy; A[2 * jq + 1] = b.zw;
    }
    #pragma unroll
    for (int k = 0; k < 64; ++k) {
        const float hv = B[k >> 1][k & 1];
        const v2f h = {hv, hv};
        const v4f* w = (const v4f*)(W3 + (size_t)k * 64);
        #pragma unroll
        for (int jq = 0; jq < 16; ++jq) {
            const v4f wa = w[jq];
            A[2 * jq]     = __builtin_elementwise_fma(h, wa.xy, A[2 * jq]);
            A[2 * jq + 1] = __builtin_elementwise_fma(h, wa.zw, A[2 * jq + 1]);
        }
    }
    v2f o2 = z2;
    #pragma unroll
    for (int jq = 0; jq < 16; ++jq) {
        const v4f wa = *(const v4f*)(Wo + 4 * jq);
        o2 = __builtin_elementwise_fma(__builtin_elementwise_max(A[2 * jq], z2),     wa.xy, o2);
        o2 = __builtin_elementwise_fma(__builtin_elementwise_max(A[2 * jq + 1], z2), wa.zw, o2);
    }
    out[p] = o2.x + o2.y + bo[0];
}

// ---------------- fallback (ws too small): R1-style fused ----------------
__global__ __launch_bounds__(256, 2)
void hashpinn_fused(const float* __restrict__ x,
                    const float* __restrict__ table,
                    const float* __restrict__ W1, const float* __restrict__ b1,
                    const float* __restrict__ W2, const float* __restrict__ b2,
                    const float* __restrict__ W3, const float* __restrict__ b3,
                    const float* __restrict__ Wo, const float* __restrict__ bo,
                    float* __restrict__ out, int n, ResArr rv)
{
    const int p = blockIdx.x * 256 + threadIdx.x;
    if (p >= n) return;
    const float px = x[3*p+0], py = x[3*p+1], pz = x[3*p+2];
    float feat[32];
    #pragma unroll
    for (int l = 0; l < 16; ++l) {
        const int res = rv.r[l];
        const float rf = (float)(res - 1);
        const float fx = px*rf, fy = py*rf, fz = pz*rf;
        int ix=(int)floorf(fx), iy=(int)floorf(fy), iz=(int)floorf(fz);
        ix=min(max(ix,0),res-2); iy=min(max(iy,0),res-2); iz=min(max(iz,0),res-2);
        const float tx=fx-(float)ix, ty=fy-(float)iy, tz=fz-(float)iz;
        const float sx=1.f-tx, sy=1.f-ty, sz=1.f-tz;
        const float2* tbl=(const float2*)table+(size_t)l*HASH_SZ;
        const bool dense=((long long)res*res*res<=(long long)HASH_SZ);
        float a0=0.f, a1=0.f;
        #pragma unroll
        for (int c=0;c<8;++c){
            const uint32_t cx=(uint32_t)(ix+((c>>2)&1));
            const uint32_t cy=(uint32_t)(iy+((c>>1)&1));
            const uint32_t cz=(uint32_t)(iz+(c&1));
            uint32_t idx = dense ? cx+(uint32_t)res*(cy+(uint32_t)res*cz)
                                 : ((cx*1u ^ cy*PR2 ^ cz*PR3)&HMASK);
            const float2 v=tbl[idx];
            const float w=(((c>>2)&1)?tx:sx)*(((c>>1)&1)?ty:sy)*((c&1)?tz:sz);
            a0=fmaf(w,v.x,a0); a1=fmaf(w,v.y,a1);
        }
        feat[2*l]=a0; feat[2*l+1]=a1;
    }
    float A[64], B[64];
    #pragma unroll
    for (int j=0;j<64;++j) A[j]=b1[j];
    #pragma unroll
    for (int k=0;k<32;++k){ const float h=feat[k];
        #pragma unroll
        for (int j=0;j<64;++j) A[j]=fmaf(h,W1[k*64+j],A[j]); }
    #pragma unroll 1
    for (int it=0;it<2;++it){
        const float* W = it?W3:W2; const float* bb = it?b3:b2;
        #pragma unroll
        for (int j=0;j<64;++j){ A[j]=fmaxf(A[j],0.f); B[j]=bb[j]; }
        #pragma unroll
        for (int k=0;k<64;++k){ const float h=A[k];
            #pragma unroll
            for (int j=0;j<64;++j) B[j]=fmaf(h,W[k*64+j],B[j]); }
        #pragma unroll
        for (int j=0;j<64;++j) A[j]=B[j];
    }
    float o=bo[0];
    #pragma unroll
    for (int j=0;j<64;++j) o=fmaf(fmaxf(A[j],0.f),Wo[j],o);
    out[p]=o;
}

static inline void launch_encode(int nlev, const float* x, const float* table,
                                 v2f* featT, int n, int lb, const ResArr& rv,
                                 hipStream_t stream) {
    const dim3 g(4096), b(256);
    switch (nlev) {
        case 1: hipLaunchKernelGGL(encode_k<1>, g, b, 0, stream, x, table, featT, n, lb, rv); break;
        case 2: hipLaunchKernelGGL(encode_k<2>, g, b, 0, stream, x, table, featT, n, lb, rv); break;
        case 3: hipLaunchKernelGGL(encode_k<3>, g, b, 0, stream, x, table, featT, n, lb, rv); break;
        case 4: hipLaunchKernelGGL(encode_k<4>, g, b, 0, stream, x, table, featT, n, lb, rv); break;
        case 5: hipLaunchKernelGGL(encode_k<5>, g, b, 0, stream, x, table, featT, n, lb, rv); break;
        case 6: hipLaunchKernelGGL(encode_k<6>, g, b, 0, stream, x, table, featT, n, lb, rv); break;
        case 7: hipLaunchKernelGGL(encode_k<7>, g, b, 0, stream, x, table, featT, n, lb, rv); break;
        default: hipLaunchKernelGGL(encode_k<8>, g, b, 0, stream, x, table, featT, n, lb, rv); break;
    }
}

extern "C" void kernel_launch(void* const* d_in, const int* in_sizes, int n_in,
                              void* d_out, int out_size, void* d_ws, size_t ws_size,
                              hipStream_t stream) {
    const float* x     = (const float*)d_in[0];
    const float* table = (const float*)d_in[1];
    const float* W1    = (const float*)d_in[2];
    const float* b1    = (const float*)d_in[3];
    const float* W2    = (const float*)d_in[4];
    const float* b2    = (const float*)d_in[5];
    const float* W3    = (const float*)d_in[6];
    const float* b3    = (const float*)d_in[7];
    const float* Wo    = (const float*)d_in[8];
    const float* bo    = (const float*)d_in[9];
    float* out = (float*)d_out;

    const int n = in_sizes[0] / 3;

    ResArr rv;
    const double scale = std::exp2(std::log2(2048.0 / 16.0) / 15.0);
    for (int l = 0; l < 16; ++l)
        rv.r[l] = (int)std::ceil(16.0 * std::pow(scale, (double)l));

    int dense_end = 0;
    while (dense_end < 16) {
        long long r = rv.r[dense_end];
        if (r * r * r <= (long long)HASH_SZ) ++dense_end; else break;
    }
    if (dense_end > 8) dense_end = 8;

    const size_t feat_bytes = (size_t)n * 16 * sizeof(v2f);
    const size_t wb_bytes = 20480 * sizeof(unsigned short);

    if (ws_size >= feat_bytes + wb_bytes) {
        v2f* featT = (v2f*)d_ws;
        unsigned short* wb = (unsigned short*)((char*)d_ws + feat_bytes);

        hipLaunchKernelGGL(prep_weights, dim3(1), dim3(256), 0, stream, W1, W2, W3, wb);

        if (dense_end > 0)
            launch_encode(dense_end, x, table, featT, n, 0, rv, stream);
        for (int l = dense_end; l < 16; ++l)
            launch_encode(1, x, table, featT, n, l, rv, stream);

        const int nblocks = (n + 127) / 128;   // 128 pts/block (4 waves x 32)
        hipLaunchKernelGGL(mlp_mfma, dim3(nblocks), dim3(256), 0, stream,
                           featT, wb, b1, b2, b3, Wo, bo, out, n);
    } else if (ws_size >= feat_bytes) {
        v2f* featT = (v2f*)d_ws;
        if (dense_end > 0)
            launch_encode(dense_end, x, table, featT, n, 0, rv, stream);
        for (int l = dense_end; l < 16; ++l)
            launch_encode(1, x, table, featT, n, l, rv, stream);
        hipLaunchKernelGGL(mlp_forward, dim3((n + 255) / 256), dim3(256), 0, stream,
                           featT, W1, b1, W2, b2, W3, b3, Wo, bo, out, n);
    } else {
        hipLaunchKernelGGL(hashpinn_fused, dim3((n + 255) / 256), dim3(256), 0, stream,
                           x, table, W1, b1, W2, b2, W3, b3, Wo, bo, out, n, rv);
    }
}